// Round 8
// baseline (248.877 us; speedup 1.0000x reference)
//
#include <hip/hip_runtime.h>
#include <math.h>

#define T_LEN 512
#define B_N   1024
#define K_N   48
#define START_TAG (K_N - 2)
#define STOP_TAG  (K_N - 1)
#define NEG   -10000.0f

// One wave (64 threads) per batch; lane j owns state j (row j of E = exp(trans)).
// Scaled-exponential domain: q_j = exp(alpha_j - C).
//   s_j  = sum_k E[j,k] * q_k   (k=0..47; col 47 = STOP has E=exp(-1e4)=0)
//   q'_j = F_j * inv * s_j,  F_j = exp(feat[t,b,j]), inv = rcp(q_0), C += log(q_0)
//
// Broadcast of q: LDS — 1 ds_write_b32 + 12 ds_read_b128 (all lanes read the
// same address = HW broadcast, no conflicts, no barrier needed: single-wave
// workgroup + in-order same-wave DS pipe). R7 used 47 v_readlane -> SGPRs,
// which was issue-bound (~400cy VALU/step) plus VALU->SGPR->VALU hazard
// stalls; LDS halves the instruction stream.
//
// Hard-won, load-bearing details:
//  * amdgpu_waves_per_eu(1,1): without it the allocator budgets 32 VGPRs and
//    spills E to scratch (R3/R4: 355us). With it E is register-resident.
//  * Feat loads UNCONDITIONAL (clamped indices, no branch) — R5: branches
//    around VMEM defeat static vmcnt tracking -> vmcnt(0) every step.
//  * NO register rotation in a rolled loop — R6: rotation movs force a
//    vmcnt(0) drain per step (~900cy HBM latency each). Fixed 512-step trip,
//    statically-unrolled 8-step ping-pong phases; per-step `t<len` cndmask
//    reproduces the reference mask (freeze alpha) semantics.

#define REP48(M) M(0)M(1)M(2)M(3)M(4)M(5)M(6)M(7)M(8)M(9)M(10)M(11)M(12) \
  M(13)M(14)M(15)M(16)M(17)M(18)M(19)M(20)M(21)M(22)M(23)M(24)M(25)M(26) \
  M(27)M(28)M(29)M(30)M(31)M(32)M(33)M(34)M(35)M(36)M(37)M(38)M(39)M(40) \
  M(41)M(42)M(43)M(44)M(45)M(46)M(47)

// Dot group: states k0..k3 from one float4 broadcast.
#define G4(k0,k1,k2,k3,V) \
        a0 = fmaf(E##k0, V.x, a0); a1 = fmaf(E##k1, V.y, a1); \
        a2 = fmaf(E##k2, V.z, a2); a3 = fmaf(E##k3, V.w, a3);

// One recursion step at time TT consuming raw feat value FVAL.
// Invariant alpha_j = C + log(q_j); updated only when TT < len.
#define STEP(TT, FVAL) do { \
        q_lds[lane] = q; \
        float4 v0 = qv4[0],  v1 = qv4[1],  v2  = qv4[2],  v3  = qv4[3], \
               v4 = qv4[4],  v5 = qv4[5],  v6  = qv4[6],  v7  = qv4[7], \
               v8 = qv4[8],  v9 = qv4[9],  v10 = qv4[10], v11 = qv4[11]; \
        const float s0v  = v0.x; \
        const bool  live = (s0v > 0.0f);            /* false only at t==0 */ \
        const float inv  = live ? __builtin_amdgcn_rcpf(s0v) : 1.0f; \
        const float dC   = live ? __logf(s0v) : 0.0f; \
        const bool  on   = ((TT) < len); \
        C += on ? dC : 0.0f; \
        const float scale = __expf(FVAL) * inv; \
        float a0 = 0.f, a1 = 0.f, a2 = 0.f, a3 = 0.f; \
        G4(0,1,2,3,v0)     G4(4,5,6,7,v1)     G4(8,9,10,11,v2) \
        G4(12,13,14,15,v3) G4(16,17,18,19,v4) G4(20,21,22,23,v5) \
        G4(24,25,26,27,v6) G4(28,29,30,31,v7) G4(32,33,34,35,v8) \
        G4(36,37,38,39,v9) G4(40,41,42,43,v10) G4(44,45,46,47,v11) \
        const float ssum = (a0 + a1) + (a2 + a3); \
        q = on ? ssum * scale : q; \
    } while (0)

__global__ __launch_bounds__(64)
__attribute__((amdgpu_waves_per_eu(1, 1)))
void crf_fused_kernel(
    const float* __restrict__ feats,    // (T, B, K)
    const float* __restrict__ trans,    // (K, K)
    const int*   __restrict__ tags,     // (B, T)
    const int*   __restrict__ lengths,  // (B,)
    float* __restrict__ out)
{
    const int b      = blockIdx.x;
    const int lane   = threadIdx.x;
    const int len    = lengths[b];
    const int lm1    = len - 1;
    const int lane_c = (lane < K_N) ? lane : (K_N - 1);   // clamp: all addrs valid

    __shared__ __align__(16) float q_lds[64];
    const float4* qv4 = (const float4*)q_lds;

    // E row in named scalars (VGPR-resident). Lanes >= K_N clamp to row 47
    // and compute junk-but-finite q forever — q_lds[48..63] is never read.
    const float* tr = trans + lane_c * K_N;
#define DECL_E(k) float E##k = __expf(tr[k]);
    REP48(DECL_E)
#undef DECL_E

    const float*  fb = feats + (size_t)b * K_N;
    const size_t  sT = (size_t)B_N * K_N;

    float q = (lane == START_TAG) ? 1.0f : 0.0f;
    float C = 0.0f;

    // Ping-pong prefetch buffers, statically indexed (pure registers).
    float f0[8], f1[8];
    #pragma unroll
    for (int i = 0; i < 8; ++i) {
        int r = (i < lm1) ? i : lm1;
        f0[i] = fb[(size_t)r * sT + lane_c];
    }

    #pragma unroll 1
    for (int blk = 0; blk < T_LEN / 16; ++blk) {
        const int t0 = blk * 16;
        // Phase A: prefetch rows t0+8..t0+15 into f1; run steps t0..t0+7 on f0.
        #pragma unroll
        for (int i = 0; i < 8; ++i) {
            int r = t0 + 8 + i; r = (r < lm1) ? r : lm1;
            f1[i] = fb[(size_t)r * sT + lane_c];
        }
        #pragma unroll
        for (int i = 0; i < 8; ++i) STEP(t0 + i, f0[i]);
        // Phase B: prefetch rows t0+16..t0+23 into f0; run steps t0+8..t0+15 on f1.
        #pragma unroll
        for (int i = 0; i < 8; ++i) {
            int r = t0 + 16 + i; r = (r < lm1) ? r : lm1;
            f0[i] = fb[(size_t)r * sT + lane_c];
        }
        #pragma unroll
        for (int i = 0; i < 8; ++i) STEP(t0 + 8 + i, f1[i]);
    }

    // log_z = C + log(q_j) + trans[STOP, j], logsumexp over lanes.
    float v = (lane < K_N && q > 0.0f)
            ? C + __logf(q) + trans[STOP_TAG * K_N + lane] : -INFINITY;
    float mz = v;
    #pragma unroll
    for (int off = 32; off >= 1; off >>= 1)
        mz = fmaxf(mz, __shfl_xor(mz, off));
    float e = __expf(v - mz);
    float se = e;
    #pragma unroll
    for (int off = 32; off >= 1; off >>= 1)
        se += __shfl_xor(se, off);
    float log_z = mz + __logf(se);

    // Gold path score: lanes stripe over t.
    float gsum = 0.0f;
    for (int t = lane; t < len; t += 64) {
        int next = tags[(size_t)b * T_LEN + t];
        int prev = (t == 0) ? START_TAG : tags[(size_t)b * T_LEN + t - 1];
        gsum += trans[next * K_N + prev]
              + fb[(size_t)t * sT + next];
    }
    #pragma unroll
    for (int off = 32; off >= 1; off >>= 1)
        gsum += __shfl_xor(gsum, off);

    if (lane == 0) {
        int last = tags[(size_t)b * T_LEN + len - 1];
        float gold = gsum + trans[STOP_TAG * K_N + last];
        atomicAdd(out, log_z - gold);
    }
}

extern "C" void kernel_launch(void* const* d_in, const int* in_sizes, int n_in,
                              void* d_out, int out_size, void* d_ws, size_t ws_size,
                              hipStream_t stream) {
    const float* feats   = (const float*)d_in[0];
    const float* trans   = (const float*)d_in[1];
    const int*   tags    = (const int*)d_in[2];
    const int*   lengths = (const int*)d_in[3];
    float* out = (float*)d_out;

    hipMemsetAsync(out, 0, sizeof(float) * out_size, stream);
    crf_fused_kernel<<<B_N, 64, 0, stream>>>(feats, trans, tags, lengths, out);
}